// Round 3
// baseline (195.567 us; speedup 1.0000x reference)
//
#include <hip/hip_runtime.h>
#include <hip/hip_bf16.h>

#define BB 2
#define NN 2048
#define CC 768
#define HH 12
#define DD 64
#define MM 4096
#define N3 2304

typedef __attribute__((ext_vector_type(8))) short bf16x8;
typedef __attribute__((ext_vector_type(4))) float f32x4;

// 0.125 (1/sqrt(D)) * log2(e) folded into Q so softmax runs in base-2 units
#define QSCALE 0.18033688011112043f

__device__ __forceinline__ unsigned short f2bf(float f) {
    union { float f; unsigned u; } v; v.f = f;
    unsigned r = v.u + 0x7FFFu + ((v.u >> 16) & 1u);
    return (unsigned short)(r >> 16);
}

// RNE cast via HIP intrinsic — compiler lowers this better than the bit-trick (m240)
__device__ __forceinline__ unsigned short f2bf_rn(float f) {
    union { __hip_bfloat16 h; unsigned short u; } v;
    v.h = __float2bfloat16(f);
    return v.u;
}

__device__ __forceinline__ float exp2_hw(float x) {
    float r;
    asm("v_exp_f32 %0, %1" : "=v"(r) : "v"(x));
    return r;
}

// loads elements [0..3] and [16..19] from p (bf16 A/B fragment k-pattern)
__device__ __forceinline__ bf16x8 ld_frag(const unsigned short* p) {
    bf16x8 r;
    __builtin_memcpy(&r, p, 8);
    __builtin_memcpy((char*)&r + 8, p + 16, 8);
    return r;
}

// swizzled frag load from a [64][64]-short tile with 16B-unit XOR swizzle
__device__ __forceinline__ bf16x8 ld_frag_sw(const unsigned short* base, int row, int colsh) {
    const int rx = row & 7;
    const unsigned short* p0 = base + row * 64 + ((((colsh) >> 3) ^ rx) << 3) + (colsh & 7);
    const int c2 = colsh + 16;
    const unsigned short* p1 = base + row * 64 + (((c2 >> 3) ^ rx) << 3) + (c2 & 7);
    bf16x8 r;
    __builtin_memcpy(&r, p0, 8);
    __builtin_memcpy((char*)&r + 8, p1, 8);
    return r;
}

__global__ void k_cvt(const float* __restrict__ s, unsigned short* __restrict__ d, int n4) {
    int i = blockIdx.x * blockDim.x + threadIdx.x;
    int st = gridDim.x * blockDim.x;
    for (; i < n4; i += st) {
        float4 v = ((const float4*)s)[i];
        ushort4 o;
        o.x = f2bf(v.x); o.y = f2bf(v.y); o.z = f2bf(v.z); o.w = f2bf(v.w);
        ((ushort4*)d)[i] = o;
    }
}

// transpose+convert: src f32 [R][Cc] -> dst bf16 [Cc][R]; grid (Cc/64, R/64)
__global__ void k_cvtT(const float* __restrict__ s, unsigned short* __restrict__ d,
                       int R, int Cc) {
    __shared__ unsigned short t[64][72];
    const int c0 = blockIdx.x * 64, r0 = blockIdx.y * 64;
    const int tr = threadIdx.x >> 4;
    const int tc = (threadIdx.x & 15) * 4;
#pragma unroll
    for (int i = 0; i < 4; i++) {
        int r = tr + i * 16;
        float4 v = *(const float4*)(s + (size_t)(r0 + r) * Cc + c0 + tc);
        t[tc + 0][r] = f2bf(v.x);
        t[tc + 1][r] = f2bf(v.y);
        t[tc + 2][r] = f2bf(v.z);
        t[tc + 3][r] = f2bf(v.w);
    }
    __syncthreads();
    const int wr = threadIdx.x >> 2;
    const int wc = (threadIdx.x & 3) * 16;
    *(uint4*)(d + (size_t)(c0 + wr) * R + r0 + wc)     = *(uint4*)&t[wr][wc];
    *(uint4*)(d + (size_t)(c0 + wr) * R + r0 + wc + 8) = *(uint4*)&t[wr][wc + 8];
}

// ---------------- GEMM1: qkv = x @ W_qkv + b, fused RoPE ----------------
// grid (32, 18), block 256 (4 waves as 2x2). Tile 128x128, BK=32. Wt is [N3][CC].
__launch_bounds__(256)
__global__ void k_qkv(const unsigned short* __restrict__ xb,
                      const unsigned short* __restrict__ wt,
                      const float* __restrict__ bias,
                      const float* __restrict__ sinp,
                      const float* __restrict__ cosp,
                      unsigned short* __restrict__ qws,
                      unsigned short* __restrict__ kws,
                      unsigned short* __restrict__ vws) {
    __shared__ unsigned short As[128][40];   // [m][k]
    __shared__ unsigned short Bs[128][40];   // [j][k]
    const int tid = threadIdx.x;
    const int lane = tid & 63, w = tid >> 6;
    const int ql = lane & 15, lg = lane >> 4;
    const int wr = w >> 1, wc = w & 1;
    const int row0 = blockIdx.x * 128;
    const int j0 = blockIdx.y * 128;

    f32x4 acc[4][4];
#pragma unroll
    for (int a = 0; a < 4; a++)
#pragma unroll
        for (int b = 0; b < 4; b++) acc[a][b] = f32x4{0.f, 0.f, 0.f, 0.f};

    const int ar = tid >> 1, ac = (tid & 1) * 16;

    for (int k0 = 0; k0 < CC; k0 += 32) {
        uint4 a0 = *(const uint4*)(xb + (size_t)(row0 + ar) * CC + k0 + ac);
        uint4 a1 = *(const uint4*)(xb + (size_t)(row0 + ar) * CC + k0 + ac + 8);
        uint4 b0 = *(const uint4*)(wt + (size_t)(j0 + ar) * CC + k0 + ac);
        uint4 b1 = *(const uint4*)(wt + (size_t)(j0 + ar) * CC + k0 + ac + 8);
        *(uint4*)&As[ar][ac]     = a0;
        *(uint4*)&As[ar][ac + 8] = a1;
        *(uint4*)&Bs[ar][ac]     = b0;
        *(uint4*)&Bs[ar][ac + 8] = b1;
        __syncthreads();

        bf16x8 af[4], bfr[4];
#pragma unroll
        for (int fr = 0; fr < 4; fr++) af[fr] = ld_frag(&As[wr * 64 + fr * 16 + ql][lg * 4]);
#pragma unroll
        for (int fn = 0; fn < 4; fn++) bfr[fn] = ld_frag(&Bs[wc * 64 + fn * 16 + ql][lg * 4]);
#pragma unroll
        for (int fr = 0; fr < 4; fr++)
#pragma unroll
            for (int fn = 0; fn < 4; fn++)
                acc[fr][fn] = __builtin_amdgcn_mfma_f32_16x16x32_bf16(af[fr], bfr[fn], acc[fr][fn], 0, 0, 0);
        __syncthreads();
    }

    // epilogue: C/D layout row=(lg*4+reg), col=ql
    const int j0w = j0 + wc * 64;
    const int t = j0w / CC;
    const int h = (j0w % CC) >> 6;
    float vals[4][4][4];
#pragma unroll
    for (int fr = 0; fr < 4; fr++)
#pragma unroll
        for (int fn = 0; fn < 4; fn++) {
            float bj = bias[j0w + fn * 16 + ql];
#pragma unroll
            for (int r = 0; r < 4; r++) vals[fr][fn][r] = acc[fr][fn][r] + bj;
        }
    if (t < 2) {
        unsigned short* outp = (t == 0) ? qws : kws;
        const float qs = (t == 0) ? QSCALE : 1.0f;
#pragma unroll
        for (int fr = 0; fr < 4; fr++)
#pragma unroll
            for (int r = 0; r < 4; r++) {
                int m = row0 + wr * 64 + fr * 16 + lg * 4 + r;
                int b = m >> 11, n = m & (NN - 1);
#pragma unroll
                for (int fn = 0; fn < 4; fn++) {
                    int d = fn * 16 + ql;
                    float cv = cosp[n * DD + d], sv = sinp[n * DD + d];
                    float other = vals[fr][fn ^ 2][r];  // partner at d +/- 32
                    float rv = (vals[fr][fn][r] * cv + ((fn < 2) ? -other : other) * sv) * qs;
                    outp[((size_t)(b * HH + h) * NN + n) * DD + d] = f2bf(rv);
                }
            }
    } else {
#pragma unroll
        for (int fr = 0; fr < 4; fr++)
#pragma unroll
            for (int r = 0; r < 4; r++) {
                int m = row0 + wr * 64 + fr * 16 + lg * 4 + r;
                int b = m >> 11, n = m & (NN - 1);
#pragma unroll
                for (int fn = 0; fn < 4; fn++) {
                    int d = fn * 16 + ql;
                    vws[((size_t)(b * HH + h) * DD + d) * NN + n] = f2bf(vals[fr][fn][r]);
                }
            }
    }
}

// ---------------- Attention (flash, S^T / O^T, dbuf + swizzled LDS) ----------------
// grid (32, 24), block 256 (4 waves). Wave owns 16 q; block stages 64-key K/V tiles.
__launch_bounds__(256)
__global__ void k_attn(const unsigned short* __restrict__ qws,
                       const unsigned short* __restrict__ kws,
                       const unsigned short* __restrict__ vws,
                       unsigned short* __restrict__ yws) {
    __shared__ unsigned short Ks[2][64 * 64];  // [kk][d], 16B-unit XOR swizzled
    __shared__ unsigned short Vs[2][64 * 64];  // [d][kk], same swizzle
    const int tid = threadIdx.x;
    const int lane = tid & 63, w = tid >> 6;
    const int ql = lane & 15, lg = lane >> 4;
    const int bh = blockIdx.y;
    const int qw = blockIdx.x * 64 + w * 16;
    const unsigned short* Qp = qws + (size_t)bh * NN * DD;
    const unsigned short* Kp = kws + (size_t)bh * NN * DD;
    const unsigned short* Vp = vws + (size_t)bh * DD * NN;

    // Q fragments hoisted (B-operand of S^T): col q = ql, k = d (pre-scaled by QSCALE)
    bf16x8 qf[2];
#pragma unroll
    for (int kb = 0; kb < 2; kb++)
        qf[kb] = ld_frag(Qp + (size_t)(qw + ql) * DD + kb * 32 + lg * 4);

    f32x4 oacc[4];
#pragma unroll
    for (int a = 0; a < 4; a++) oacc[a] = f32x4{0.f, 0.f, 0.f, 0.f};
    float mrun = -1e30f, lrun = 0.f;

    const int srow = tid >> 3;   // 0..31
    const int sunit = tid & 7;   // 16B unit within 128B row

    // prologue: stage tile 0
#pragma unroll
    for (int p = 0; p < 2; p++) {
        int row = p * 32 + srow;
        int off = row * 64 + (((sunit) ^ (row & 7)) << 3);
        *(uint4*)&Ks[0][off] = *(const uint4*)(Kp + (size_t)row * DD + sunit * 8);
        *(uint4*)&Vs[0][off] = *(const uint4*)(Vp + (size_t)row * NN + sunit * 8);
    }
    __syncthreads();

    const int NT = NN / 64;
    int cur = 0;
    for (int kt = 0; kt < NT; kt++) {
        // issue next tile's global loads early (hide latency under compute) [T14]
        uint4 kn[2], vn[2];
        const bool hasn = (kt + 1 < NT);
        if (hasn) {
#pragma unroll
            for (int p = 0; p < 2; p++) {
                int row = p * 32 + srow;
                kn[p] = *(const uint4*)(Kp + (size_t)((kt + 1) * 64 + row) * DD + sunit * 8);
                vn[p] = *(const uint4*)(Vp + (size_t)row * NN + (kt + 1) * 64 + sunit * 8);
            }
        }
        const unsigned short* Kc = Ks[cur];
        const unsigned short* Vc = Vs[cur];

        // S^T[kk][q] = sum_d K[kk][d] * Qs[q][d]   (already in log2 units)
        f32x4 sacc[4];
#pragma unroll
        for (int a = 0; a < 4; a++) sacc[a] = f32x4{0.f, 0.f, 0.f, 0.f};
        __builtin_amdgcn_s_setprio(1);
#pragma unroll
        for (int kb = 0; kb < 2; kb++) {
            bf16x8 kf[4];
#pragma unroll
            for (int fr = 0; fr < 4; fr++) kf[fr] = ld_frag_sw(Kc, fr * 16 + ql, kb * 32 + lg * 4);
#pragma unroll
            for (int fr = 0; fr < 4; fr++)
                sacc[fr] = __builtin_amdgcn_mfma_f32_16x16x32_bf16(kf[fr], qf[kb], sacc[fr], 0, 0, 0);
        }
        __builtin_amdgcn_s_setprio(0);

        // online softmax per q-column (col q = ql, stats in-lane + shfl over lg)
        float m0 = fmaxf(fmaxf(sacc[0][0], sacc[0][1]), fmaxf(sacc[0][2], sacc[0][3]));
        float m1 = fmaxf(fmaxf(sacc[1][0], sacc[1][1]), fmaxf(sacc[1][2], sacc[1][3]));
        float m2 = fmaxf(fmaxf(sacc[2][0], sacc[2][1]), fmaxf(sacc[2][2], sacc[2][3]));
        float m3 = fmaxf(fmaxf(sacc[3][0], sacc[3][1]), fmaxf(sacc[3][2], sacc[3][3]));
        float tm = fmaxf(fmaxf(m0, m1), fmaxf(m2, m3));
        tm = fmaxf(tm, __shfl_xor(tm, 16));
        tm = fmaxf(tm, __shfl_xor(tm, 32));
        // defer-max: only rescale when the running max grows by more than 8 (log2) [T13]
        if (__any(tm > mrun + 8.0f)) {
            float mn = fmaxf(mrun, tm);
            float scl = exp2_hw(mrun - mn);
            lrun *= scl;
#pragma unroll
            for (int db = 0; db < 4; db++) oacc[db] *= scl;
            mrun = mn;
        }
        float ts = 0.f;
#pragma unroll
        for (int fr = 0; fr < 4; fr++)
#pragma unroll
            for (int r = 0; r < 4; r++) {
                float p = exp2_hw(sacc[fr][r] - mrun);
                sacc[fr][r] = p;
                ts += p;
            }
        ts += __shfl_xor(ts, 16);
        ts += __shfl_xor(ts, 32);
        lrun += ts;

        // in-lane repack: S^T C/D frag -> B-operand frags of PV
        bf16x8 pB[2];
#pragma unroll
        for (int kkb = 0; kkb < 2; kkb++) {
            bf16x8 t8;
#pragma unroll
            for (int e = 0; e < 8; e++)
                t8[e] = (short)f2bf_rn(sacc[kkb * 2 + (e >> 2)][e & 3]);
            pB[kkb] = t8;
        }

        // O^T[d][q] += sum_kk V^T[d][kk] P^T[kk][q]
        __builtin_amdgcn_s_setprio(1);
#pragma unroll
        for (int db = 0; db < 4; db++) {
            bf16x8 va[2];
#pragma unroll
            for (int kkb = 0; kkb < 2; kkb++) va[kkb] = ld_frag_sw(Vc, db * 16 + ql, kkb * 32 + lg * 4);
#pragma unroll
            for (int kkb = 0; kkb < 2; kkb++)
                oacc[db] = __builtin_amdgcn_mfma_f32_16x16x32_bf16(va[kkb], pB[kkb], oacc[db], 0, 0, 0);
        }
        __builtin_amdgcn_s_setprio(0);

        if (hasn) {
            // write next tile (disjoint buffer), single barrier per iteration
#pragma unroll
            for (int p = 0; p < 2; p++) {
                int row = p * 32 + srow;
                int off = row * 64 + (((sunit) ^ (row & 7)) << 3);
                *(uint4*)&Ks[cur ^ 1][off] = kn[p];
                *(uint4*)&Vs[cur ^ 1][off] = vn[p];
            }
            __syncthreads();
            cur ^= 1;
        }
    }

    // epilogue: O^T frag row = d, col = q; vectorized 8B stores
    const int b = bh / HH, h = bh % HH;
    float inv = 1.0f / lrun;
    int q = qw + ql;
    unsigned short* yp = yws + (size_t)(b * NN + q) * CC + h * DD + lg * 4;
#pragma unroll
    for (int db = 0; db < 4; db++) {
        ushort4 o;
        o.x = f2bf(oacc[db][0] * inv);
        o.y = f2bf(oacc[db][1] * inv);
        o.z = f2bf(oacc[db][2] * inv);
        o.w = f2bf(oacc[db][3] * inv);
        *(ushort4*)(yp + db * 16) = o;
    }
}

// ---------------- GEMM2: out = y @ W_out + b_out (f32 out) ----------------
// grid (32, 6), block 256 (4 waves as 2x2). Tile 128x128. Wt is [CC][CC].
__launch_bounds__(256)
__global__ void k_out(const unsigned short* __restrict__ yb,
                      const unsigned short* __restrict__ wt,
                      const float* __restrict__ bias,
                      float* __restrict__ out) {
    __shared__ unsigned short As[128][40];
    __shared__ unsigned short Bs[128][40];
    const int tid = threadIdx.x;
    const int lane = tid & 63, w = tid >> 6;
    const int ql = lane & 15, lg = lane >> 4;
    const int wr = w >> 1, wc = w & 1;
    const int row0 = blockIdx.x * 128;
    const int j0 = blockIdx.y * 128;

    f32x4 acc[4][4];
#pragma unroll
    for (int a = 0; a < 4; a++)
#pragma unroll
        for (int b = 0; b < 4; b++) acc[a][b] = f32x4{0.f, 0.f, 0.f, 0.f};

    const int ar = tid >> 1, ac = (tid & 1) * 16;

    for (int k0 = 0; k0 < CC; k0 += 32) {
        uint4 a0 = *(const uint4*)(yb + (size_t)(row0 + ar) * CC + k0 + ac);
        uint4 a1 = *(const uint4*)(yb + (size_t)(row0 + ar) * CC + k0 + ac + 8);
        uint4 b0 = *(const uint4*)(wt + (size_t)(j0 + ar) * CC + k0 + ac);
        uint4 b1 = *(const uint4*)(wt + (size_t)(j0 + ar) * CC + k0 + ac + 8);
        *(uint4*)&As[ar][ac]     = a0;
        *(uint4*)&As[ar][ac + 8] = a1;
        *(uint4*)&Bs[ar][ac]     = b0;
        *(uint4*)&Bs[ar][ac + 8] = b1;
        __syncthreads();

        bf16x8 af[4], bfr[4];
#pragma unroll
        for (int fr = 0; fr < 4; fr++) af[fr] = ld_frag(&As[wr * 64 + fr * 16 + ql][lg * 4]);
#pragma unroll
        for (int fn = 0; fn < 4; fn++) bfr[fn] = ld_frag(&Bs[wc * 64 + fn * 16 + ql][lg * 4]);
#pragma unroll
        for (int fr = 0; fr < 4; fr++)
#pragma unroll
            for (int fn = 0; fn < 4; fn++)
                acc[fr][fn] = __builtin_amdgcn_mfma_f32_16x16x32_bf16(af[fr], bfr[fn], acc[fr][fn], 0, 0, 0);
        __syncthreads();
    }

#pragma unroll
    for (int fr = 0; fr < 4; fr++)
#pragma unroll
        for (int fn = 0; fn < 4; fn++) {
            float bj = bias[j0 + wc * 64 + fn * 16 + ql];
#pragma unroll
            for (int r = 0; r < 4; r++) {
                int m = row0 + wr * 64 + fr * 16 + lg * 4 + r;
                out[(size_t)m * CC + j0 + wc * 64 + fn * 16 + ql] = acc[fr][fn][r] + bj;
            }
        }
}

extern "C" void kernel_launch(void* const* d_in, const int* in_sizes, int n_in,
                              void* d_out, int out_size, void* d_ws, size_t ws_size,
                              hipStream_t stream) {
    const float* x    = (const float*)d_in[0];
    const float* sinp = (const float*)d_in[1];
    const float* cosp = (const float*)d_in[2];
    const float* wqkv = (const float*)d_in[3];
    const float* bqkv = (const float*)d_in[4];
    const float* wout = (const float*)d_in[5];
    const float* bout = (const float*)d_in[6];
    float* out = (float*)d_out;
    char* ws = (char*)d_ws;

    unsigned short* xb  = (unsigned short*)(ws);            // 4096x768 bf16
    unsigned short* wqb = (unsigned short*)(ws + 6291456);  // Wt_qkv [2304][768]
    unsigned short* wob = (unsigned short*)(ws + 9830400);  // Wt_out [768][768]
    unsigned short* qws = (unsigned short*)(ws + 11010048);
    unsigned short* kws = (unsigned short*)(ws + 17301504);
    unsigned short* vws = (unsigned short*)(ws + 23592960);
    unsigned short* yws = (unsigned short*)(ws + 29884416);
    if (ws_size < 36175872) return;

    k_cvt<<<dim3(512), dim3(256), 0, stream>>>(x, xb, MM * CC / 4);
    k_cvtT<<<dim3(36, 12), dim3(256), 0, stream>>>(wqkv, wqb, CC, N3);
    k_cvtT<<<dim3(12, 12), dim3(256), 0, stream>>>(wout, wob, CC, CC);
    k_qkv<<<dim3(32, 18), dim3(256), 0, stream>>>(xb, wqb, bqkv, sinp, cosp, qws, kws, vws);
    k_attn<<<dim3(32, 24), dim3(256), 0, stream>>>(qws, kws, vws, yws);
    k_out<<<dim3(32, 6), dim3(256), 0, stream>>>(yws, wob, bout, out);
}

// Round 4
// 149.802 us; speedup vs baseline: 1.3055x; 1.3055x over previous
//
#include <hip/hip_runtime.h>
#include <hip/hip_bf16.h>

#define BB 2
#define NN 2048
#define CC 768
#define HH 12
#define DD 64
#define MM 4096
#define N3 2304

typedef __attribute__((ext_vector_type(8))) short bf16x8;
typedef __attribute__((ext_vector_type(4))) float f32x4;

// 0.125 (1/sqrt(D)) * log2(e) folded into Q so softmax runs in base-2 units
#define QSCALE 0.18033688011112043f

__device__ __forceinline__ unsigned short f2bf(float f) {
    union { float f; unsigned u; } v; v.f = f;
    unsigned r = v.u + 0x7FFFu + ((v.u >> 16) & 1u);
    return (unsigned short)(r >> 16);
}

__device__ __forceinline__ float exp2_hw(float x) {
    float r;
    asm("v_exp_f32 %0, %1" : "=v"(r) : "v"(x));
    return r;
}

// loads elements [0..3] and [16..19] from p (bf16 A/B fragment k-pattern)
__device__ __forceinline__ bf16x8 ld_frag(const unsigned short* p) {
    bf16x8 r;
    __builtin_memcpy(&r, p, 8);
    __builtin_memcpy((char*)&r + 8, p + 16, 8);
    return r;
}

__global__ void k_cvt(const float* __restrict__ s, unsigned short* __restrict__ d, int n4) {
    int i = blockIdx.x * blockDim.x + threadIdx.x;
    int st = gridDim.x * blockDim.x;
    for (; i < n4; i += st) {
        float4 v = ((const float4*)s)[i];
        ushort4 o;
        o.x = f2bf(v.x); o.y = f2bf(v.y); o.z = f2bf(v.z); o.w = f2bf(v.w);
        ((ushort4*)d)[i] = o;
    }
}

// transpose+convert: src f32 [R][Cc] -> dst bf16 [Cc][R]; grid (Cc/64, R/64)
__global__ void k_cvtT(const float* __restrict__ s, unsigned short* __restrict__ d,
                       int R, int Cc) {
    __shared__ unsigned short t[64][72];
    const int c0 = blockIdx.x * 64, r0 = blockIdx.y * 64;
    const int tr = threadIdx.x >> 4;
    const int tc = (threadIdx.x & 15) * 4;
#pragma unroll
    for (int i = 0; i < 4; i++) {
        int r = tr + i * 16;
        float4 v = *(const float4*)(s + (size_t)(r0 + r) * Cc + c0 + tc);
        t[tc + 0][r] = f2bf(v.x);
        t[tc + 1][r] = f2bf(v.y);
        t[tc + 2][r] = f2bf(v.z);
        t[tc + 3][r] = f2bf(v.w);
    }
    __syncthreads();
    const int wr = threadIdx.x >> 2;
    const int wc = (threadIdx.x & 3) * 16;
    *(uint4*)(d + (size_t)(c0 + wr) * R + r0 + wc)     = *(uint4*)&t[wr][wc];
    *(uint4*)(d + (size_t)(c0 + wr) * R + r0 + wc + 8) = *(uint4*)&t[wr][wc + 8];
}

// ---------------- GEMM1: qkv = x @ W_qkv + b, fused RoPE ----------------
// grid (32, 36), block 256. Tile 128(M) x 64(N), BK=32. Wt is [N3][CC] (transposed).
__launch_bounds__(256)
__global__ void k_qkv(const unsigned short* __restrict__ xb,
                      const unsigned short* __restrict__ wt,
                      const float* __restrict__ bias,
                      const float* __restrict__ sinp,
                      const float* __restrict__ cosp,
                      unsigned short* __restrict__ qws,
                      unsigned short* __restrict__ kws,
                      unsigned short* __restrict__ vws) {
    __shared__ unsigned short As[128][40];   // [m][k]
    __shared__ unsigned short Bs[64][40];    // [j][k]
    const int tid = threadIdx.x;
    const int lane = tid & 63, w = tid >> 6;
    const int ql = lane & 15, lg = lane >> 4;
    const int row0 = blockIdx.x * 128;
    const int j0 = blockIdx.y * 64;

    f32x4 acc[2][4];
#pragma unroll
    for (int a = 0; a < 2; a++)
#pragma unroll
        for (int b = 0; b < 4; b++) acc[a][b] = f32x4{0.f, 0.f, 0.f, 0.f};

    const int ar = tid >> 1, ac = (tid & 1) * 16;
    const int jr = tid >> 2, kc = (tid & 3) * 8;

    for (int k0 = 0; k0 < CC; k0 += 32) {
        uint4 av0 = *(const uint4*)(xb + (size_t)(row0 + ar) * CC + k0 + ac);
        uint4 av1 = *(const uint4*)(xb + (size_t)(row0 + ar) * CC + k0 + ac + 8);
        uint4 bv  = *(const uint4*)(wt + (size_t)(j0 + jr) * CC + k0 + kc);
        *(uint4*)&As[ar][ac]     = av0;
        *(uint4*)&As[ar][ac + 8] = av1;
        *(uint4*)&Bs[jr][kc]     = bv;
        __syncthreads();

        bf16x8 af[2], bfr[4];
#pragma unroll
        for (int fr = 0; fr < 2; fr++) af[fr] = ld_frag(&As[w * 32 + fr * 16 + ql][lg * 4]);
#pragma unroll
        for (int fn = 0; fn < 4; fn++) bfr[fn] = ld_frag(&Bs[fn * 16 + ql][lg * 4]);
#pragma unroll
        for (int fr = 0; fr < 2; fr++)
#pragma unroll
            for (int fn = 0; fn < 4; fn++)
                acc[fr][fn] = __builtin_amdgcn_mfma_f32_16x16x32_bf16(af[fr], bfr[fn], acc[fr][fn], 0, 0, 0);
        __syncthreads();
    }

    float vals[2][4][4];
#pragma unroll
    for (int fr = 0; fr < 2; fr++)
#pragma unroll
        for (int fn = 0; fn < 4; fn++) {
            float bj = bias[j0 + fn * 16 + ql];
#pragma unroll
            for (int r = 0; r < 4; r++) vals[fr][fn][r] = acc[fr][fn][r] + bj;
        }
    const int t = j0 / CC;
    const int h = (j0 % CC) >> 6;
    if (t < 2) {
        unsigned short* outp = (t == 0) ? qws : kws;
        const float qs = (t == 0) ? QSCALE : 1.0f;
#pragma unroll
        for (int fr = 0; fr < 2; fr++)
#pragma unroll
            for (int r = 0; r < 4; r++) {
                int m = row0 + w * 32 + fr * 16 + lg * 4 + r;
                int b = m >> 11, n = m & (NN - 1);
#pragma unroll
                for (int fn = 0; fn < 4; fn++) {
                    int d = fn * 16 + ql;
                    float cv = cosp[n * DD + d], sv = sinp[n * DD + d];
                    float other = vals[fr][fn ^ 2][r];  // partner at d +/- 32
                    float rv = (vals[fr][fn][r] * cv + ((fn < 2) ? -other : other) * sv) * qs;
                    outp[((size_t)(b * HH + h) * NN + n) * DD + d] = f2bf(rv);
                }
            }
    } else {
#pragma unroll
        for (int fr = 0; fr < 2; fr++)
#pragma unroll
            for (int r = 0; r < 4; r++) {
                int m = row0 + w * 32 + fr * 16 + lg * 4 + r;
                int b = m >> 11, n = m & (NN - 1);
#pragma unroll
                for (int fn = 0; fn < 4; fn++) {
                    int d = fn * 16 + ql;
                    vws[((size_t)(b * HH + h) * DD + d) * NN + n] = f2bf(vals[fr][fn][r]);
                }
            }
    }
}

// ---------------- Attention (flash, S^T / O^T formulation) ----------------
// grid 1536 (1-D, XCD-swizzled), block 128 (2 waves). Wave owns 16 q; block 32 q.
// XCD swizzle: all 64 q-blocks of one (b,h) land on the same XCD (d % 8 class),
// so K/V stay in that XCD's L2 (4 MiB >> 512 KiB per head).
__launch_bounds__(128)
__global__ void k_attn(const unsigned short* __restrict__ qws,
                       const unsigned short* __restrict__ kws,
                       const unsigned short* __restrict__ vws,
                       unsigned short* __restrict__ yws) {
    __shared__ unsigned short Ks[64][72];  // [kk][d]
    __shared__ unsigned short Vs[64][72];  // [d][kk]
    const int tid = threadIdx.x;
    const int lane = tid & 63, w = tid >> 6;
    const int ql = lane & 15, lg = lane >> 4;
    const int d0 = blockIdx.x;
    const int bh = (d0 & 7) + 8 * (d0 >> 9);     // 0..23, constant per XCD class
    const int qb = (d0 >> 3) & 63;               // 0..63
    const int qw = qb * 32 + w * 16;
    const unsigned short* Qp = qws + (size_t)bh * NN * DD;
    const unsigned short* Kp = kws + (size_t)bh * NN * DD;
    const unsigned short* Vp = vws + (size_t)bh * DD * NN;

    // Q fragments hoisted (B-operand of S^T): col q = ql, k = d (pre-scaled by QSCALE)
    bf16x8 qf[2];
#pragma unroll
    for (int kb = 0; kb < 2; kb++)
        qf[kb] = ld_frag(Qp + (size_t)(qw + ql) * DD + kb * 32 + lg * 4);

    f32x4 oacc[4];
#pragma unroll
    for (int a = 0; a < 4; a++) oacc[a] = f32x4{0.f, 0.f, 0.f, 0.f};
    float mrun = -1e30f, lrun = 0.f;

    const int sr = tid >> 1, sh = (tid & 1) * 32;  // 64 rows x 2 half-rows

    for (int kt = 0; kt < NN / 64; kt++) {
        *(uint4*)&Ks[sr][sh]      = *(const uint4*)(Kp + (size_t)(kt * 64 + sr) * DD + sh);
        *(uint4*)&Ks[sr][sh + 8]  = *(const uint4*)(Kp + (size_t)(kt * 64 + sr) * DD + sh + 8);
        *(uint4*)&Ks[sr][sh + 16] = *(const uint4*)(Kp + (size_t)(kt * 64 + sr) * DD + sh + 16);
        *(uint4*)&Ks[sr][sh + 24] = *(const uint4*)(Kp + (size_t)(kt * 64 + sr) * DD + sh + 24);
        *(uint4*)&Vs[sr][sh]      = *(const uint4*)(Vp + (size_t)sr * NN + kt * 64 + sh);
        *(uint4*)&Vs[sr][sh + 8]  = *(const uint4*)(Vp + (size_t)sr * NN + kt * 64 + sh + 8);
        *(uint4*)&Vs[sr][sh + 16] = *(const uint4*)(Vp + (size_t)sr * NN + kt * 64 + sh + 16);
        *(uint4*)&Vs[sr][sh + 24] = *(const uint4*)(Vp + (size_t)sr * NN + kt * 64 + sh + 24);
        __syncthreads();

        // S^T[kk][q] = sum_d K[kk][d] * Qs[q][d]   (already in log2 units)
        f32x4 sacc[4];
#pragma unroll
        for (int a = 0; a < 4; a++) sacc[a] = f32x4{0.f, 0.f, 0.f, 0.f};
        __builtin_amdgcn_s_setprio(1);
#pragma unroll
        for (int kb = 0; kb < 2; kb++) {
            bf16x8 kf[4];
#pragma unroll
            for (int fr = 0; fr < 4; fr++) kf[fr] = ld_frag(&Ks[fr * 16 + ql][kb * 32 + lg * 4]);
#pragma unroll
            for (int fr = 0; fr < 4; fr++)
                sacc[fr] = __builtin_amdgcn_mfma_f32_16x16x32_bf16(kf[fr], qf[kb], sacc[fr], 0, 0, 0);
        }
        __builtin_amdgcn_s_setprio(0);

        // online softmax per q-column (col q = ql, stats in-lane + shfl over lg)
        float m0 = fmaxf(fmaxf(sacc[0][0], sacc[0][1]), fmaxf(sacc[0][2], sacc[0][3]));
        float m1 = fmaxf(fmaxf(sacc[1][0], sacc[1][1]), fmaxf(sacc[1][2], sacc[1][3]));
        float m2 = fmaxf(fmaxf(sacc[2][0], sacc[2][1]), fmaxf(sacc[2][2], sacc[2][3]));
        float m3 = fmaxf(fmaxf(sacc[3][0], sacc[3][1]), fmaxf(sacc[3][2], sacc[3][3]));
        float tm = fmaxf(fmaxf(m0, m1), fmaxf(m2, m3));
        tm = fmaxf(tm, __shfl_xor(tm, 16));
        tm = fmaxf(tm, __shfl_xor(tm, 32));
        // defer-max: only rescale when the running max grows by more than 8 (log2) [T13]
        if (__any(tm > mrun + 8.0f)) {
            float mn = fmaxf(mrun, tm);
            float scl = exp2_hw(mrun - mn);
            lrun *= scl;
#pragma unroll
            for (int db = 0; db < 4; db++) oacc[db] *= scl;
            mrun = mn;
        }
        float ts = 0.f;
#pragma unroll
        for (int fr = 0; fr < 4; fr++)
#pragma unroll
            for (int r = 0; r < 4; r++) {
                float p = exp2_hw(sacc[fr][r] - mrun);
                sacc[fr][r] = p;
                ts += p;
            }
        ts += __shfl_xor(ts, 16);
        ts += __shfl_xor(ts, 32);
        lrun += ts;

        // in-lane repack: S^T C/D frag -> B-operand frags of PV
        bf16x8 pB[2];
#pragma unroll
        for (int kkb = 0; kkb < 2; kkb++) {
            bf16x8 t8;
#pragma unroll
            for (int e = 0; e < 8; e++)
                t8[e] = (short)f2bf(sacc[kkb * 2 + (e >> 2)][e & 3]);
            pB[kkb] = t8;
        }

        // O^T[d][q] += sum_kk V^T[d][kk] P^T[kk][q]
        __builtin_amdgcn_s_setprio(1);
#pragma unroll
        for (int db = 0; db < 4; db++) {
            bf16x8 va[2];
#pragma unroll
            for (int kkb = 0; kkb < 2; kkb++) va[kkb] = ld_frag(&Vs[db * 16 + ql][kkb * 32 + lg * 4]);
#pragma unroll
            for (int kkb = 0; kkb < 2; kkb++)
                oacc[db] = __builtin_amdgcn_mfma_f32_16x16x32_bf16(va[kkb], pB[kkb], oacc[db], 0, 0, 0);
        }
        __builtin_amdgcn_s_setprio(0);
        __syncthreads();
    }

    // epilogue: O^T frag row = d, col = q; vectorized 8B stores
    const int b = bh / HH, h = bh % HH;
    float inv = 1.0f / lrun;
    int q = qw + ql;
    unsigned short* yp = yws + (size_t)(b * NN + q) * CC + h * DD + lg * 4;
#pragma unroll
    for (int db = 0; db < 4; db++) {
        ushort4 o;
        o.x = f2bf(oacc[db][0] * inv);
        o.y = f2bf(oacc[db][1] * inv);
        o.z = f2bf(oacc[db][2] * inv);
        o.w = f2bf(oacc[db][3] * inv);
        *(ushort4*)(yp + db * 16) = o;
    }
}

// ---------------- GEMM2: out = y @ W_out + b_out (f32 out) ----------------
// Wot is [CC][CC] transposed.
__launch_bounds__(256)
__global__ void k_out(const unsigned short* __restrict__ yb,
                      const unsigned short* __restrict__ wt,
                      const float* __restrict__ bias,
                      float* __restrict__ out) {
    __shared__ unsigned short As[128][40];
    __shared__ unsigned short Bs[64][40];
    const int tid = threadIdx.x;
    const int lane = tid & 63, w = tid >> 6;
    const int ql = lane & 15, lg = lane >> 4;
    const int row0 = blockIdx.x * 128;
    const int j0 = blockIdx.y * 64;

    f32x4 acc[2][4];
#pragma unroll
    for (int a = 0; a < 2; a++)
#pragma unroll
        for (int b = 0; b < 4; b++) acc[a][b] = f32x4{0.f, 0.f, 0.f, 0.f};

    const int ar = tid >> 1, ac = (tid & 1) * 16;
    const int jr = tid >> 2, kc = (tid & 3) * 8;

    for (int k0 = 0; k0 < CC; k0 += 32) {
        uint4 av0 = *(const uint4*)(yb + (size_t)(row0 + ar) * CC + k0 + ac);
        uint4 av1 = *(const uint4*)(yb + (size_t)(row0 + ar) * CC + k0 + ac + 8);
        uint4 bv  = *(const uint4*)(wt + (size_t)(j0 + jr) * CC + k0 + kc);
        *(uint4*)&As[ar][ac]     = av0;
        *(uint4*)&As[ar][ac + 8] = av1;
        *(uint4*)&Bs[jr][kc]     = bv;
        __syncthreads();

        bf16x8 af[2], bfr[4];
#pragma unroll
        for (int fr = 0; fr < 2; fr++) af[fr] = ld_frag(&As[w * 32 + fr * 16 + ql][lg * 4]);
#pragma unroll
        for (int fn = 0; fn < 4; fn++) bfr[fn] = ld_frag(&Bs[fn * 16 + ql][lg * 4]);
#pragma unroll
        for (int fr = 0; fr < 2; fr++)
#pragma unroll
            for (int fn = 0; fn < 4; fn++)
                acc[fr][fn] = __builtin_amdgcn_mfma_f32_16x16x32_bf16(af[fr], bfr[fn], acc[fr][fn], 0, 0, 0);
        __syncthreads();
    }

#pragma unroll
    for (int fr = 0; fr < 2; fr++)
#pragma unroll
        for (int fn = 0; fn < 4; fn++) {
            float bj = bias[j0 + fn * 16 + ql];
#pragma unroll
            for (int r = 0; r < 4; r++) {
                int m = row0 + w * 32 + fr * 16 + lg * 4 + r;
                out[(size_t)m * CC + j0 + fn * 16 + ql] = acc[fr][fn][r] + bj;
            }
        }
}

extern "C" void kernel_launch(void* const* d_in, const int* in_sizes, int n_in,
                              void* d_out, int out_size, void* d_ws, size_t ws_size,
                              hipStream_t stream) {
    const float* x    = (const float*)d_in[0];
    const float* sinp = (const float*)d_in[1];
    const float* cosp = (const float*)d_in[2];
    const float* wqkv = (const float*)d_in[3];
    const float* bqkv = (const float*)d_in[4];
    const float* wout = (const float*)d_in[5];
    const float* bout = (const float*)d_in[6];
    float* out = (float*)d_out;
    char* ws = (char*)d_ws;

    unsigned short* xb  = (unsigned short*)(ws);            // 4096x768 bf16
    unsigned short* wqb = (unsigned short*)(ws + 6291456);  // Wt_qkv [2304][768]
    unsigned short* wob = (unsigned short*)(ws + 9830400);  // Wt_out [768][768]
    unsigned short* qws = (unsigned short*)(ws + 11010048);
    unsigned short* kws = (unsigned short*)(ws + 17301504);
    unsigned short* vws = (unsigned short*)(ws + 23592960);
    unsigned short* yws = (unsigned short*)(ws + 29884416);
    if (ws_size < 36175872) return;

    k_cvt<<<dim3(512), dim3(256), 0, stream>>>(x, xb, MM * CC / 4);
    k_cvtT<<<dim3(36, 12), dim3(256), 0, stream>>>(wqkv, wqb, CC, N3);
    k_cvtT<<<dim3(12, 12), dim3(256), 0, stream>>>(wout, wob, CC, CC);
    k_qkv<<<dim3(32, 36), dim3(256), 0, stream>>>(xb, wqb, bqkv, sinp, cosp, qws, kws, vws);
    k_attn<<<dim3(1536), dim3(128), 0, stream>>>(qws, kws, vws, yws);
    k_out<<<dim3(32, 12), dim3(256), 0, stream>>>(yws, wob, bout, out);
}

// Round 5
// 140.096 us; speedup vs baseline: 1.3960x; 1.0693x over previous
//
#include <hip/hip_runtime.h>
#include <hip/hip_bf16.h>

#define BB 2
#define NN 2048
#define CC 768
#define HH 12
#define DD 64
#define MM 4096
#define N3 2304

typedef __attribute__((ext_vector_type(8))) short bf16x8;
typedef __attribute__((ext_vector_type(4))) float f32x4;

// 0.125 (1/sqrt(D)) * log2(e) folded into Q so softmax runs in base-2 units
#define QSCALE 0.18033688011112043f

__device__ __forceinline__ unsigned short f2bf(float f) {
    union { float f; unsigned u; } v; v.f = f;
    unsigned r = v.u + 0x7FFFu + ((v.u >> 16) & 1u);
    return (unsigned short)(r >> 16);
}

// RNE cast — compiler lowers pairs to v_cvt_pk_bf16_f32 (m240: don't hand-write)
__device__ __forceinline__ short f2bf_rn(float f) {
    union { __hip_bfloat16 h; short s; } v;
    v.h = __float2bfloat16(f);
    return v.s;
}

__device__ __forceinline__ float exp2_hw(float x) {
    float r;
    asm("v_exp_f32 %0, %1" : "=v"(r) : "v"(x));
    return r;
}

// loads elements [0..3] and [16..19] from p (bf16 A/B fragment k-pattern)
__device__ __forceinline__ bf16x8 ld_frag(const unsigned short* p) {
    bf16x8 r;
    __builtin_memcpy(&r, p, 8);
    __builtin_memcpy((char*)&r + 8, p + 16, 8);
    return r;
}

__global__ void k_cvt(const float* __restrict__ s, unsigned short* __restrict__ d, int n4) {
    int i = blockIdx.x * blockDim.x + threadIdx.x;
    int st = gridDim.x * blockDim.x;
    for (; i < n4; i += st) {
        float4 v = ((const float4*)s)[i];
        ushort4 o;
        o.x = f2bf(v.x); o.y = f2bf(v.y); o.z = f2bf(v.z); o.w = f2bf(v.w);
        ((ushort4*)d)[i] = o;
    }
}

// transpose+convert: src f32 [R][Cc] -> dst bf16 [Cc][R]; grid (Cc/64, R/64)
__global__ void k_cvtT(const float* __restrict__ s, unsigned short* __restrict__ d,
                       int R, int Cc) {
    __shared__ unsigned short t[64][72];
    const int c0 = blockIdx.x * 64, r0 = blockIdx.y * 64;
    const int tr = threadIdx.x >> 4;
    const int tc = (threadIdx.x & 15) * 4;
#pragma unroll
    for (int i = 0; i < 4; i++) {
        int r = tr + i * 16;
        float4 v = *(const float4*)(s + (size_t)(r0 + r) * Cc + c0 + tc);
        t[tc + 0][r] = f2bf(v.x);
        t[tc + 1][r] = f2bf(v.y);
        t[tc + 2][r] = f2bf(v.z);
        t[tc + 3][r] = f2bf(v.w);
    }
    __syncthreads();
    const int wr = threadIdx.x >> 2;
    const int wc = (threadIdx.x & 3) * 16;
    *(uint4*)(d + (size_t)(c0 + wr) * R + r0 + wc)     = *(uint4*)&t[wr][wc];
    *(uint4*)(d + (size_t)(c0 + wr) * R + r0 + wc + 8) = *(uint4*)&t[wr][wc + 8];
}

// ---------------- GEMM1: qkv = x @ W_qkv + b, fused RoPE ----------------
// grid (32, 36), block 256. Tile 128(M) x 64(N), BK=32. Wt is [N3][CC] (transposed).
__launch_bounds__(256)
__global__ void k_qkv(const unsigned short* __restrict__ xb,
                      const unsigned short* __restrict__ wt,
                      const float* __restrict__ bias,
                      const float* __restrict__ sinp,
                      const float* __restrict__ cosp,
                      unsigned short* __restrict__ qws,
                      unsigned short* __restrict__ kws,
                      unsigned short* __restrict__ vws) {
    __shared__ unsigned short As[128][40];   // [m][k]
    __shared__ unsigned short Bs[64][40];    // [j][k]
    const int tid = threadIdx.x;
    const int lane = tid & 63, w = tid >> 6;
    const int ql = lane & 15, lg = lane >> 4;
    const int row0 = blockIdx.x * 128;
    const int j0 = blockIdx.y * 64;

    f32x4 acc[2][4];
#pragma unroll
    for (int a = 0; a < 2; a++)
#pragma unroll
        for (int b = 0; b < 4; b++) acc[a][b] = f32x4{0.f, 0.f, 0.f, 0.f};

    const int ar = tid >> 1, ac = (tid & 1) * 16;
    const int jr = tid >> 2, kc = (tid & 3) * 8;

    for (int k0 = 0; k0 < CC; k0 += 32) {
        uint4 av0 = *(const uint4*)(xb + (size_t)(row0 + ar) * CC + k0 + ac);
        uint4 av1 = *(const uint4*)(xb + (size_t)(row0 + ar) * CC + k0 + ac + 8);
        uint4 bv  = *(const uint4*)(wt + (size_t)(j0 + jr) * CC + k0 + kc);
        *(uint4*)&As[ar][ac]     = av0;
        *(uint4*)&As[ar][ac + 8] = av1;
        *(uint4*)&Bs[jr][kc]     = bv;
        __syncthreads();

        bf16x8 af[2], bfr[4];
#pragma unroll
        for (int fr = 0; fr < 2; fr++) af[fr] = ld_frag(&As[w * 32 + fr * 16 + ql][lg * 4]);
#pragma unroll
        for (int fn = 0; fn < 4; fn++) bfr[fn] = ld_frag(&Bs[fn * 16 + ql][lg * 4]);
#pragma unroll
        for (int fr = 0; fr < 2; fr++)
#pragma unroll
            for (int fn = 0; fn < 4; fn++)
                acc[fr][fn] = __builtin_amdgcn_mfma_f32_16x16x32_bf16(af[fr], bfr[fn], acc[fr][fn], 0, 0, 0);
        __syncthreads();
    }

    float vals[2][4][4];
#pragma unroll
    for (int fr = 0; fr < 2; fr++)
#pragma unroll
        for (int fn = 0; fn < 4; fn++) {
            float bj = bias[j0 + fn * 16 + ql];
#pragma unroll
            for (int r = 0; r < 4; r++) vals[fr][fn][r] = acc[fr][fn][r] + bj;
        }
    const int t = j0 / CC;
    const int h = (j0 % CC) >> 6;
    if (t < 2) {
        unsigned short* outp = (t == 0) ? qws : kws;
        const float qs = (t == 0) ? QSCALE : 1.0f;
#pragma unroll
        for (int fr = 0; fr < 2; fr++)
#pragma unroll
            for (int r = 0; r < 4; r++) {
                int m = row0 + w * 32 + fr * 16 + lg * 4 + r;
                int b = m >> 11, n = m & (NN - 1);
#pragma unroll
                for (int fn = 0; fn < 4; fn++) {
                    int d = fn * 16 + ql;
                    float cv = cosp[n * DD + d], sv = sinp[n * DD + d];
                    float other = vals[fr][fn ^ 2][r];  // partner at d +/- 32
                    float rv = (vals[fr][fn][r] * cv + ((fn < 2) ? -other : other) * sv) * qs;
                    outp[((size_t)(b * HH + h) * NN + n) * DD + d] = f2bf(rv);
                }
            }
    } else {
#pragma unroll
        for (int fr = 0; fr < 2; fr++)
#pragma unroll
            for (int r = 0; r < 4; r++) {
                int m = row0 + w * 32 + fr * 16 + lg * 4 + r;
                int b = m >> 11, n = m & (NN - 1);
#pragma unroll
                for (int fn = 0; fn < 4; fn++) {
                    int d = fn * 16 + ql;
                    vws[((size_t)(b * HH + h) * DD + d) * NN + n] = f2bf(vals[fr][fn][r]);
                }
            }
    }
}

// ---------------- Attention (flash, S^T / O^T, dbuf, XCD-swizzled) ----------------
// grid 768 (1-D), block 256 (4 waves). Wave owns 16 q; block 64 q; 64-key K/V tiles.
// XCD swizzle: d0&7 selects the XCD class; each class serves 3 heads -> K/V L2-resident.
// Double-buffer: prefetch kt+1 into regs before compute, write to buf^1 after, 1 barrier.
__launch_bounds__(256)
__global__ void k_attn(const unsigned short* __restrict__ qws,
                       const unsigned short* __restrict__ kws,
                       const unsigned short* __restrict__ vws,
                       unsigned short* __restrict__ yws) {
    __shared__ unsigned short Ks[2][64][72];  // [buf][kk][d]
    __shared__ unsigned short Vs[2][64][72];  // [buf][d][kk]
    const int tid = threadIdx.x;
    const int lane = tid & 63, w = tid >> 6;
    const int ql = lane & 15, lg = lane >> 4;
    const int d0 = blockIdx.x;
    const int bh = (d0 & 7) + 8 * (d0 >> 8);     // 0..23, 3 heads per XCD class
    const int qb = (d0 >> 3) & 31;               // 0..31
    const int qw = qb * 64 + w * 16;
    const unsigned short* Qp = qws + (size_t)bh * NN * DD;
    const unsigned short* Kp = kws + (size_t)bh * NN * DD;
    const unsigned short* Vp = vws + (size_t)bh * DD * NN;

    // Q fragments hoisted (B-operand of S^T): col q = ql, k = d (pre-scaled by QSCALE)
    bf16x8 qf[2];
#pragma unroll
    for (int kb = 0; kb < 2; kb++)
        qf[kb] = ld_frag(Qp + (size_t)(qw + ql) * DD + kb * 32 + lg * 4);

    f32x4 oacc[4];
#pragma unroll
    for (int a = 0; a < 4; a++) oacc[a] = f32x4{0.f, 0.f, 0.f, 0.f};
    float mrun = -1e30f, lrun = 0.f;

    const int sr = tid >> 2, sc = (tid & 3) * 16;

    // prologue: stage tile 0
    *(uint4*)&Ks[0][sr][sc]     = *(const uint4*)(Kp + (size_t)sr * DD + sc);
    *(uint4*)&Ks[0][sr][sc + 8] = *(const uint4*)(Kp + (size_t)sr * DD + sc + 8);
    *(uint4*)&Vs[0][sr][sc]     = *(const uint4*)(Vp + (size_t)sr * NN + sc);
    *(uint4*)&Vs[0][sr][sc + 8] = *(const uint4*)(Vp + (size_t)sr * NN + sc + 8);
    __syncthreads();

    const int NT = NN / 64;
    int cur = 0;
    for (int kt = 0; kt < NT; kt++) {
        // issue next tile's global loads early (L2-local after XCD swizzle) [T14]
        uint4 kn0, kn1, vn0, vn1;
        const bool hasn = (kt + 1 < NT);
        if (hasn) {
            kn0 = *(const uint4*)(Kp + (size_t)((kt + 1) * 64 + sr) * DD + sc);
            kn1 = *(const uint4*)(Kp + (size_t)((kt + 1) * 64 + sr) * DD + sc + 8);
            vn0 = *(const uint4*)(Vp + (size_t)sr * NN + (kt + 1) * 64 + sc);
            vn1 = *(const uint4*)(Vp + (size_t)sr * NN + (kt + 1) * 64 + sc + 8);
        }
        const unsigned short (*Kc)[72] = Ks[cur];
        const unsigned short (*Vc)[72] = Vs[cur];

        // S^T[kk][q] = sum_d K[kk][d] * Qs[q][d]   (already in log2 units)
        f32x4 sacc[4];
#pragma unroll
        for (int a = 0; a < 4; a++) sacc[a] = f32x4{0.f, 0.f, 0.f, 0.f};
        __builtin_amdgcn_s_setprio(1);
#pragma unroll
        for (int kb = 0; kb < 2; kb++) {
            bf16x8 kf[4];
#pragma unroll
            for (int fr = 0; fr < 4; fr++) kf[fr] = ld_frag(&Kc[fr * 16 + ql][kb * 32 + lg * 4]);
#pragma unroll
            for (int fr = 0; fr < 4; fr++)
                sacc[fr] = __builtin_amdgcn_mfma_f32_16x16x32_bf16(kf[fr], qf[kb], sacc[fr], 0, 0, 0);
        }
        __builtin_amdgcn_s_setprio(0);

        // online softmax per q-column (col q = ql, stats in-lane + shfl over lg)
        float m0 = fmaxf(fmaxf(sacc[0][0], sacc[0][1]), fmaxf(sacc[0][2], sacc[0][3]));
        float m1 = fmaxf(fmaxf(sacc[1][0], sacc[1][1]), fmaxf(sacc[1][2], sacc[1][3]));
        float m2 = fmaxf(fmaxf(sacc[2][0], sacc[2][1]), fmaxf(sacc[2][2], sacc[2][3]));
        float m3 = fmaxf(fmaxf(sacc[3][0], sacc[3][1]), fmaxf(sacc[3][2], sacc[3][3]));
        float tm = fmaxf(fmaxf(m0, m1), fmaxf(m2, m3));
        tm = fmaxf(tm, __shfl_xor(tm, 16));
        tm = fmaxf(tm, __shfl_xor(tm, 32));
        // defer-max: only rescale when the running max grows by more than 8 (log2) [T13]
        if (__any(tm > mrun + 8.0f)) {
            float mn = fmaxf(mrun, tm);
            float scl = exp2_hw(mrun - mn);
            lrun *= scl;
#pragma unroll
            for (int db = 0; db < 4; db++) oacc[db] *= scl;
            mrun = mn;
        }
        float ts = 0.f;
#pragma unroll
        for (int fr = 0; fr < 4; fr++)
#pragma unroll
            for (int r = 0; r < 4; r++) {
                float p = exp2_hw(sacc[fr][r] - mrun);
                sacc[fr][r] = p;
                ts += p;
            }
        ts += __shfl_xor(ts, 16);
        ts += __shfl_xor(ts, 32);
        lrun += ts;

        // in-lane repack: S^T C/D frag -> B-operand frags of PV (RNE pk-cvt)
        bf16x8 pB[2];
#pragma unroll
        for (int kkb = 0; kkb < 2; kkb++) {
            bf16x8 t8;
#pragma unroll
            for (int e = 0; e < 8; e++)
                t8[e] = f2bf_rn(sacc[kkb * 2 + (e >> 2)][e & 3]);
            pB[kkb] = t8;
        }

        // O^T[d][q] += sum_kk V^T[d][kk] P^T[kk][q]
        __builtin_amdgcn_s_setprio(1);
#pragma unroll
        for (int db = 0; db < 4; db++) {
            bf16x8 va[2];
#pragma unroll
            for (int kkb = 0; kkb < 2; kkb++) va[kkb] = ld_frag(&Vc[db * 16 + ql][kkb * 32 + lg * 4]);
#pragma unroll
            for (int kkb = 0; kkb < 2; kkb++)
                oacc[db] = __builtin_amdgcn_mfma_f32_16x16x32_bf16(va[kkb], pB[kkb], oacc[db], 0, 0, 0);
        }
        __builtin_amdgcn_s_setprio(0);

        if (hasn) {
            // write next tile into the other buffer (disjoint), single barrier per iter
            *(uint4*)&Ks[cur ^ 1][sr][sc]     = kn0;
            *(uint4*)&Ks[cur ^ 1][sr][sc + 8] = kn1;
            *(uint4*)&Vs[cur ^ 1][sr][sc]     = vn0;
            *(uint4*)&Vs[cur ^ 1][sr][sc + 8] = vn1;
            __syncthreads();
            cur ^= 1;
        }
    }

    // epilogue: O^T frag row = d, col = q; vectorized 8B stores
    const int b = bh / HH, h = bh % HH;
    float inv = 1.0f / lrun;
    int q = qw + ql;
    unsigned short* yp = yws + (size_t)(b * NN + q) * CC + h * DD + lg * 4;
#pragma unroll
    for (int db = 0; db < 4; db++) {
        ushort4 o;
        o.x = f2bf(oacc[db][0] * inv);
        o.y = f2bf(oacc[db][1] * inv);
        o.z = f2bf(oacc[db][2] * inv);
        o.w = f2bf(oacc[db][3] * inv);
        *(ushort4*)(yp + db * 16) = o;
    }
}

// ---------------- GEMM2: out = y @ W_out + b_out (f32 out) ----------------
// Wot is [CC][CC] transposed.
__launch_bounds__(256)
__global__ void k_out(const unsigned short* __restrict__ yb,
                      const unsigned short* __restrict__ wt,
                      const float* __restrict__ bias,
                      float* __restrict__ out) {
    __shared__ unsigned short As[128][40];
    __shared__ unsigned short Bs[64][40];
    const int tid = threadIdx.x;
    const int lane = tid & 63, w = tid >> 6;
    const int ql = lane & 15, lg = lane >> 4;
    const int row0 = blockIdx.x * 128;
    const int j0 = blockIdx.y * 64;

    f32x4 acc[2][4];
#pragma unroll
    for (int a = 0; a < 2; a++)
#pragma unroll
        for (int b = 0; b < 4; b++) acc[a][b] = f32x4{0.f, 0.f, 0.f, 0.f};

    const int ar = tid >> 1, ac = (tid & 1) * 16;
    const int jr = tid >> 2, kc = (tid & 3) * 8;

    for (int k0 = 0; k0 < CC; k0 += 32) {
        uint4 av0 = *(const uint4*)(yb + (size_t)(row0 + ar) * CC + k0 + ac);
        uint4 av1 = *(const uint4*)(yb + (size_t)(row0 + ar) * CC + k0 + ac + 8);
        uint4 bv  = *(const uint4*)(wt + (size_t)(j0 + jr) * CC + k0 + kc);
        *(uint4*)&As[ar][ac]     = av0;
        *(uint4*)&As[ar][ac + 8] = av1;
        *(uint4*)&Bs[jr][kc]     = bv;
        __syncthreads();

        bf16x8 af[2], bfr[4];
#pragma unroll
        for (int fr = 0; fr < 2; fr++) af[fr] = ld_frag(&As[w * 32 + fr * 16 + ql][lg * 4]);
#pragma unroll
        for (int fn = 0; fn < 4; fn++) bfr[fn] = ld_frag(&Bs[fn * 16 + ql][lg * 4]);
#pragma unroll
        for (int fr = 0; fr < 2; fr++)
#pragma unroll
            for (int fn = 0; fn < 4; fn++)
                acc[fr][fn] = __builtin_amdgcn_mfma_f32_16x16x32_bf16(af[fr], bfr[fn], acc[fr][fn], 0, 0, 0);
        __syncthreads();
    }

#pragma unroll
    for (int fr = 0; fr < 2; fr++)
#pragma unroll
        for (int fn = 0; fn < 4; fn++) {
            float bj = bias[j0 + fn * 16 + ql];
#pragma unroll
            for (int r = 0; r < 4; r++) {
                int m = row0 + w * 32 + fr * 16 + lg * 4 + r;
                out[(size_t)m * CC + j0 + fn * 16 + ql] = acc[fr][fn][r] + bj;
            }
        }
}

extern "C" void kernel_launch(void* const* d_in, const int* in_sizes, int n_in,
                              void* d_out, int out_size, void* d_ws, size_t ws_size,
                              hipStream_t stream) {
    const float* x    = (const float*)d_in[0];
    const float* sinp = (const float*)d_in[1];
    const float* cosp = (const float*)d_in[2];
    const float* wqkv = (const float*)d_in[3];
    const float* bqkv = (const float*)d_in[4];
    const float* wout = (const float*)d_in[5];
    const float* bout = (const float*)d_in[6];
    float* out = (float*)d_out;
    char* ws = (char*)d_ws;

    unsigned short* xb  = (unsigned short*)(ws);            // 4096x768 bf16
    unsigned short* wqb = (unsigned short*)(ws + 6291456);  // Wt_qkv [2304][768]
    unsigned short* wob = (unsigned short*)(ws + 9830400);  // Wt_out [768][768]
    unsigned short* qws = (unsigned short*)(ws + 11010048);
    unsigned short* kws = (unsigned short*)(ws + 17301504);
    unsigned short* vws = (unsigned short*)(ws + 23592960);
    unsigned short* yws = (unsigned short*)(ws + 29884416);
    if (ws_size < 36175872) return;

    k_cvt<<<dim3(512), dim3(256), 0, stream>>>(x, xb, MM * CC / 4);
    k_cvtT<<<dim3(36, 12), dim3(256), 0, stream>>>(wqkv, wqb, CC, N3);
    k_cvtT<<<dim3(12, 12), dim3(256), 0, stream>>>(wout, wob, CC, CC);
    k_qkv<<<dim3(32, 36), dim3(256), 0, stream>>>(xb, wqb, bqkv, sinp, cosp, qws, kws, vws);
    k_attn<<<dim3(768), dim3(256), 0, stream>>>(qws, kws, vws, yws);
    k_out<<<dim3(32, 12), dim3(256), 0, stream>>>(yws, wob, bout, out);
}

// Round 6
// 136.276 us; speedup vs baseline: 1.4351x; 1.0280x over previous
//
#include <hip/hip_runtime.h>
#include <hip/hip_bf16.h>

#define BB 2
#define NN 2048
#define CC 768
#define HH 12
#define DD 64
#define MM 4096
#define N3 2304

typedef __attribute__((ext_vector_type(8))) short bf16x8;
typedef __attribute__((ext_vector_type(4))) float f32x4;

// 0.125 (1/sqrt(D)) * log2(e) folded into Q so softmax runs in base-2 units
#define QSCALE 0.18033688011112043f

// K/V fragment-contiguous permutation: within each 32-element k-block, the
// element at offset o is stored at position p(o) = ((o&15)>>2)*8 + (o>>4)*4 + (o&3).
// Then the MFMA A-fragment for lane-group lg is the 8 contiguous shorts at
// position lg*8 (elements in exact frag order) -> single ds_read_b128.

__device__ __forceinline__ unsigned short f2bf(float f) {
    union { float f; unsigned u; } v; v.f = f;
    unsigned r = v.u + 0x7FFFu + ((v.u >> 16) & 1u);
    return (unsigned short)(r >> 16);
}

// RNE cast — compiler lowers pairs to v_cvt_pk_bf16_f32 (m240: don't hand-write)
__device__ __forceinline__ short f2bf_rn(float f) {
    union { __hip_bfloat16 h; short s; } v;
    v.h = __float2bfloat16(f);
    return v.s;
}

__device__ __forceinline__ float exp2_hw(float x) {
    float r;
    asm("v_exp_f32 %0, %1" : "=v"(r) : "v"(x));
    return r;
}

// loads elements [0..3] and [16..19] from p (bf16 A/B fragment k-pattern)
__device__ __forceinline__ bf16x8 ld_frag(const unsigned short* p) {
    bf16x8 r;
    __builtin_memcpy(&r, p, 8);
    __builtin_memcpy((char*)&r + 8, p + 16, 8);
    return r;
}

// contiguous 16B fragment load (permuted storage)
__device__ __forceinline__ bf16x8 ld_frag16(const unsigned short* p) {
    bf16x8 r;
    __builtin_memcpy(&r, p, 16);
    return r;
}

__global__ void k_cvt(const float* __restrict__ s, unsigned short* __restrict__ d, int n4) {
    int i = blockIdx.x * blockDim.x + threadIdx.x;
    int st = gridDim.x * blockDim.x;
    for (; i < n4; i += st) {
        float4 v = ((const float4*)s)[i];
        ushort4 o;
        o.x = f2bf(v.x); o.y = f2bf(v.y); o.z = f2bf(v.z); o.w = f2bf(v.w);
        ((ushort4*)d)[i] = o;
    }
}

// transpose+convert: src f32 [R][Cc] -> dst bf16 [Cc][R]; grid (Cc/64, R/64)
__global__ void k_cvtT(const float* __restrict__ s, unsigned short* __restrict__ d,
                       int R, int Cc) {
    __shared__ unsigned short t[64][72];
    const int c0 = blockIdx.x * 64, r0 = blockIdx.y * 64;
    const int tr = threadIdx.x >> 4;
    const int tc = (threadIdx.x & 15) * 4;
#pragma unroll
    for (int i = 0; i < 4; i++) {
        int r = tr + i * 16;
        float4 v = *(const float4*)(s + (size_t)(r0 + r) * Cc + c0 + tc);
        t[tc + 0][r] = f2bf(v.x);
        t[tc + 1][r] = f2bf(v.y);
        t[tc + 2][r] = f2bf(v.z);
        t[tc + 3][r] = f2bf(v.w);
    }
    __syncthreads();
    const int wr = threadIdx.x >> 2;
    const int wc = (threadIdx.x & 3) * 16;
    *(uint4*)(d + (size_t)(c0 + wr) * R + r0 + wc)     = *(uint4*)&t[wr][wc];
    *(uint4*)(d + (size_t)(c0 + wr) * R + r0 + wc + 8) = *(uint4*)&t[wr][wc + 8];
}

// ---------------- GEMM1: qkv = x @ W_qkv + b, fused RoPE ----------------
// grid (32, 36), block 256. Tile 128(M) x 64(N), BK=32. Wt is [N3][CC] (transposed).
// K and V outputs are stored with the frag-contiguous 32-block permutation.
__launch_bounds__(256)
__global__ void k_qkv(const unsigned short* __restrict__ xb,
                      const unsigned short* __restrict__ wt,
                      const float* __restrict__ bias,
                      const float* __restrict__ sinp,
                      const float* __restrict__ cosp,
                      unsigned short* __restrict__ qws,
                      unsigned short* __restrict__ kws,
                      unsigned short* __restrict__ vws) {
    __shared__ unsigned short As[128][40];   // [m][k]
    __shared__ unsigned short Bs[64][40];    // [j][k]
    const int tid = threadIdx.x;
    const int lane = tid & 63, w = tid >> 6;
    const int ql = lane & 15, lg = lane >> 4;
    const int row0 = blockIdx.x * 128;
    const int j0 = blockIdx.y * 64;

    f32x4 acc[2][4];
#pragma unroll
    for (int a = 0; a < 2; a++)
#pragma unroll
        for (int b = 0; b < 4; b++) acc[a][b] = f32x4{0.f, 0.f, 0.f, 0.f};

    const int ar = tid >> 1, ac = (tid & 1) * 16;
    const int jr = tid >> 2, kc = (tid & 3) * 8;

    for (int k0 = 0; k0 < CC; k0 += 32) {
        uint4 av0 = *(const uint4*)(xb + (size_t)(row0 + ar) * CC + k0 + ac);
        uint4 av1 = *(const uint4*)(xb + (size_t)(row0 + ar) * CC + k0 + ac + 8);
        uint4 bv  = *(const uint4*)(wt + (size_t)(j0 + jr) * CC + k0 + kc);
        *(uint4*)&As[ar][ac]     = av0;
        *(uint4*)&As[ar][ac + 8] = av1;
        *(uint4*)&Bs[jr][kc]     = bv;
        __syncthreads();

        bf16x8 af[2], bfr[4];
#pragma unroll
        for (int fr = 0; fr < 2; fr++) af[fr] = ld_frag(&As[w * 32 + fr * 16 + ql][lg * 4]);
#pragma unroll
        for (int fn = 0; fn < 4; fn++) bfr[fn] = ld_frag(&Bs[fn * 16 + ql][lg * 4]);
#pragma unroll
        for (int fr = 0; fr < 2; fr++)
#pragma unroll
            for (int fn = 0; fn < 4; fn++)
                acc[fr][fn] = __builtin_amdgcn_mfma_f32_16x16x32_bf16(af[fr], bfr[fn], acc[fr][fn], 0, 0, 0);
        __syncthreads();
    }

    float vals[2][4][4];
#pragma unroll
    for (int fr = 0; fr < 2; fr++)
#pragma unroll
        for (int fn = 0; fn < 4; fn++) {
            float bj = bias[j0 + fn * 16 + ql];
#pragma unroll
            for (int r = 0; r < 4; r++) vals[fr][fn][r] = acc[fr][fn][r] + bj;
        }
    const int t = j0 / CC;
    const int h = (j0 % CC) >> 6;
    if (t < 2) {
        unsigned short* outp = (t == 0) ? qws : kws;
        const float qs = (t == 0) ? QSCALE : 1.0f;
#pragma unroll
        for (int fr = 0; fr < 2; fr++)
#pragma unroll
            for (int r = 0; r < 4; r++) {
                int m = row0 + w * 32 + fr * 16 + lg * 4 + r;
                int b = m >> 11, n = m & (NN - 1);
#pragma unroll
                for (int fn = 0; fn < 4; fn++) {
                    int d = fn * 16 + ql;
                    float cv = cosp[n * DD + d], sv = sinp[n * DD + d];
                    float other = vals[fr][fn ^ 2][r];  // partner at d +/- 32
                    float rv = (vals[fr][fn][r] * cv + ((fn < 2) ? -other : other) * sv) * qs;
                    // K columns permuted (frag-contiguous); Q stays plain
                    int dcol = (t == 0) ? d
                             : ((fn >> 1) * 32 + (ql >> 2) * 8 + (fn & 1) * 4 + (ql & 3));
                    outp[((size_t)(b * HH + h) * NN + n) * DD + dcol] = f2bf(rv);
                }
            }
    } else {
#pragma unroll
        for (int fr = 0; fr < 2; fr++)
#pragma unroll
            for (int r = 0; r < 4; r++) {
                int m = row0 + w * 32 + fr * 16 + lg * 4 + r;
                int b = m >> 11, n = m & (NN - 1);
                // V n-columns permuted within 32-blocks: (n&31) = (fr&1)*16+lg*4+r
                int ncol = (n & ~31) + lg * 8 + (fr & 1) * 4 + r;
#pragma unroll
                for (int fn = 0; fn < 4; fn++) {
                    int d = fn * 16 + ql;
                    vws[((size_t)(b * HH + h) * DD + d) * NN + ncol] = f2bf(vals[fr][fn][r]);
                }
            }
    }
}

// ---------------- Attention (flash, S^T / O^T, dbuf, XCD-swizzled) ----------------
// grid 768 (1-D), block 128 (2 waves). Wave owns 32 q; block 64 q; 64-key K/V tiles.
// K/V in LDS with frag-contiguous permutation -> single ds_read_b128 per fragment.
__launch_bounds__(128)
__global__ void k_attn(const unsigned short* __restrict__ qws,
                       const unsigned short* __restrict__ kws,
                       const unsigned short* __restrict__ vws,
                       unsigned short* __restrict__ yws) {
    __shared__ unsigned short Ks[2][64][72];  // [buf][kk][d-permuted]
    __shared__ unsigned short Vs[2][64][72];  // [buf][d][kk-permuted]
    const int tid = threadIdx.x;
    const int lane = tid & 63, w = tid >> 6;
    const int ql = lane & 15, lg = lane >> 4;
    const int d0 = blockIdx.x;
    const int bh = (d0 & 7) + 8 * (d0 >> 8);     // 0..23, 3 heads per XCD class
    const int qb = (d0 >> 3) & 31;               // 0..31
    const int qw = qb * 64 + w * 32;
    const unsigned short* Qp = qws + (size_t)bh * NN * DD;
    const unsigned short* Kp = kws + (size_t)bh * NN * DD;
    const unsigned short* Vp = vws + (size_t)bh * DD * NN;

    // Q fragments hoisted (B-operand of S^T): col q = ql, k = d (pre-scaled, unpermuted)
    bf16x8 qf[2][2];
#pragma unroll
    for (int fn = 0; fn < 2; fn++)
#pragma unroll
        for (int kb = 0; kb < 2; kb++)
            qf[fn][kb] = ld_frag(Qp + (size_t)(qw + fn * 16 + ql) * DD + kb * 32 + lg * 4);

    f32x4 oacc[4][2];
#pragma unroll
    for (int a = 0; a < 4; a++)
#pragma unroll
        for (int b = 0; b < 2; b++) oacc[a][b] = f32x4{0.f, 0.f, 0.f, 0.f};
    float mrun[2] = {-1e30f, -1e30f}, lrun[2] = {0.f, 0.f};

    const int srow = tid >> 1;        // 0..63
    const int shalf = (tid & 1) * 32; // 32-short (one k-block) granularity

    // prologue: stage tile 0 (4 uint4 K + 4 uint4 V per thread)
#pragma unroll
    for (int j = 0; j < 4; j++) {
        *(uint4*)&Ks[0][srow][shalf + j * 8] = *(const uint4*)(Kp + (size_t)srow * DD + shalf + j * 8);
        *(uint4*)&Vs[0][srow][shalf + j * 8] = *(const uint4*)(Vp + (size_t)srow * NN + shalf + j * 8);
    }
    __syncthreads();

    const int NT = NN / 64;
    int cur = 0;
    for (int kt = 0; kt < NT; kt++) {
        // issue next tile's global loads early (L2-local after XCD swizzle) [T14]
        uint4 kn[4], vn[4];
        const bool hasn = (kt + 1 < NT);
        if (hasn) {
#pragma unroll
            for (int j = 0; j < 4; j++) {
                kn[j] = *(const uint4*)(Kp + (size_t)((kt + 1) * 64 + srow) * DD + shalf + j * 8);
                vn[j] = *(const uint4*)(Vp + (size_t)srow * NN + (kt + 1) * 64 + shalf + j * 8);
            }
        }
        const unsigned short (*Kc)[72] = Ks[cur];
        const unsigned short (*Vc)[72] = Vs[cur];

        // S^T[kk][q] = sum_d K[kk][d] * Qs[q][d]   (log2 units)
        f32x4 sacc[4][2];
#pragma unroll
        for (int a = 0; a < 4; a++)
#pragma unroll
            for (int b = 0; b < 2; b++) sacc[a][b] = f32x4{0.f, 0.f, 0.f, 0.f};
        __builtin_amdgcn_s_setprio(1);
#pragma unroll
        for (int kb = 0; kb < 2; kb++) {
            bf16x8 kf[4];
#pragma unroll
            for (int fr = 0; fr < 4; fr++)
                kf[fr] = ld_frag16(&Kc[fr * 16 + ql][kb * 32 + lg * 8]);
#pragma unroll
            for (int fr = 0; fr < 4; fr++)
#pragma unroll
                for (int fn = 0; fn < 2; fn++)
                    sacc[fr][fn] = __builtin_amdgcn_mfma_f32_16x16x32_bf16(kf[fr], qf[fn][kb], sacc[fr][fn], 0, 0, 0);
        }
        __builtin_amdgcn_s_setprio(0);

        // online softmax per q-column (col q = fn*16+ql, stats in-lane + shfl over lg)
        bf16x8 pB[2][2];
#pragma unroll
        for (int fn = 0; fn < 2; fn++) {
            float ma = fmaxf(fmaxf(sacc[0][fn][0], sacc[0][fn][1]), fmaxf(sacc[0][fn][2], sacc[0][fn][3]));
            float mb = fmaxf(fmaxf(sacc[1][fn][0], sacc[1][fn][1]), fmaxf(sacc[1][fn][2], sacc[1][fn][3]));
            float mc = fmaxf(fmaxf(sacc[2][fn][0], sacc[2][fn][1]), fmaxf(sacc[2][fn][2], sacc[2][fn][3]));
            float md = fmaxf(fmaxf(sacc[3][fn][0], sacc[3][fn][1]), fmaxf(sacc[3][fn][2], sacc[3][fn][3]));
            float tm = fmaxf(fmaxf(ma, mb), fmaxf(mc, md));
            tm = fmaxf(tm, __shfl_xor(tm, 16));
            tm = fmaxf(tm, __shfl_xor(tm, 32));
            // defer-max: rescale only when running max grows by more than 8 (log2) [T13]
            if (__any(tm > mrun[fn] + 8.0f)) {
                float mn = fmaxf(mrun[fn], tm);
                float scl = exp2_hw(mrun[fn] - mn);
                lrun[fn] *= scl;
#pragma unroll
                for (int db = 0; db < 4; db++) oacc[db][fn] *= scl;
                mrun[fn] = mn;
            }
            float ts = 0.f;
#pragma unroll
            for (int fr = 0; fr < 4; fr++)
#pragma unroll
                for (int r = 0; r < 4; r++) {
                    float p = exp2_hw(sacc[fr][fn][r] - mrun[fn]);
                    sacc[fr][fn][r] = p;
                    ts += p;
                }
            ts += __shfl_xor(ts, 16);
            ts += __shfl_xor(ts, 32);
            lrun[fn] += ts;

            // in-lane repack: S^T C/D frag -> B-operand frags of PV (RNE pk-cvt)
#pragma unroll
            for (int kkb = 0; kkb < 2; kkb++) {
                bf16x8 t8;
#pragma unroll
                for (int e = 0; e < 8; e++)
                    t8[e] = f2bf_rn(sacc[kkb * 2 + (e >> 2)][fn][e & 3]);
                pB[fn][kkb] = t8;
            }
        }

        // O^T[d][q] += sum_kk V^T[d][kk] P^T[kk][q]
        __builtin_amdgcn_s_setprio(1);
#pragma unroll
        for (int db = 0; db < 4; db++) {
            bf16x8 va[2];
#pragma unroll
            for (int kkb = 0; kkb < 2; kkb++)
                va[kkb] = ld_frag16(&Vc[db * 16 + ql][kkb * 32 + lg * 8]);
#pragma unroll
            for (int kkb = 0; kkb < 2; kkb++)
#pragma unroll
                for (int fn = 0; fn < 2; fn++)
                    oacc[db][fn] = __builtin_amdgcn_mfma_f32_16x16x32_bf16(va[kkb], pB[fn][kkb], oacc[db][fn], 0, 0, 0);
        }
        __builtin_amdgcn_s_setprio(0);

        if (hasn) {
            // write next tile into the other buffer (disjoint), single barrier per iter
#pragma unroll
            for (int j = 0; j < 4; j++) {
                *(uint4*)&Ks[cur ^ 1][srow][shalf + j * 8] = kn[j];
                *(uint4*)&Vs[cur ^ 1][srow][shalf + j * 8] = vn[j];
            }
            __syncthreads();
            cur ^= 1;
        }
    }

    // epilogue: O^T frag row = d, col = q; vectorized 8B stores
    const int b = bh / HH, h = bh % HH;
#pragma unroll
    for (int fn = 0; fn < 2; fn++) {
        float inv = 1.0f / lrun[fn];
        int q = qw + fn * 16 + ql;
        unsigned short* yp = yws + (size_t)(b * NN + q) * CC + h * DD + lg * 4;
#pragma unroll
        for (int db = 0; db < 4; db++) {
            ushort4 o;
            o.x = f2bf(oacc[db][fn][0] * inv);
            o.y = f2bf(oacc[db][fn][1] * inv);
            o.z = f2bf(oacc[db][fn][2] * inv);
            o.w = f2bf(oacc[db][fn][3] * inv);
            *(ushort4*)(yp + db * 16) = o;
        }
    }
}

// ---------------- GEMM2: out = y @ W_out + b_out (f32 out) ----------------
// Wot is [CC][CC] transposed.
__launch_bounds__(256)
__global__ void k_out(const unsigned short* __restrict__ yb,
                      const unsigned short* __restrict__ wt,
                      const float* __restrict__ bias,
                      float* __restrict__ out) {
    __shared__ unsigned short As[128][40];
    __shared__ unsigned short Bs[64][40];
    const int tid = threadIdx.x;
    const int lane = tid & 63, w = tid >> 6;
    const int ql = lane & 15, lg = lane >> 4;
    const int row0 = blockIdx.x * 128;
    const int j0 = blockIdx.y * 64;

    f32x4 acc[2][4];
#pragma unroll
    for (int a = 0; a < 2; a++)
#pragma unroll
        for (int b = 0; b < 4; b++) acc[a][b] = f32x4{0.f, 0.f, 0.f, 0.f};

    const int ar = tid >> 1, ac = (tid & 1) * 16;
    const int jr = tid >> 2, kc = (tid & 3) * 8;

    for (int k0 = 0; k0 < CC; k0 += 32) {
        uint4 av0 = *(const uint4*)(yb + (size_t)(row0 + ar) * CC + k0 + ac);
        uint4 av1 = *(const uint4*)(yb + (size_t)(row0 + ar) * CC + k0 + ac + 8);
        uint4 bv  = *(const uint4*)(wt + (size_t)(j0 + jr) * CC + k0 + kc);
        *(uint4*)&As[ar][ac]     = av0;
        *(uint4*)&As[ar][ac + 8] = av1;
        *(uint4*)&Bs[jr][kc]     = bv;
        __syncthreads();

        bf16x8 af[2], bfr[4];
#pragma unroll
        for (int fr = 0; fr < 2; fr++) af[fr] = ld_frag(&As[w * 32 + fr * 16 + ql][lg * 4]);
#pragma unroll
        for (int fn = 0; fn < 4; fn++) bfr[fn] = ld_frag(&Bs[fn * 16 + ql][lg * 4]);
#pragma unroll
        for (int fr = 0; fr < 2; fr++)
#pragma unroll
            for (int fn = 0; fn < 4; fn++)
                acc[fr][fn] = __builtin_amdgcn_mfma_f32_16x16x32_bf16(af[fr], bfr[fn], acc[fr][fn], 0, 0, 0);
        __syncthreads();
    }

#pragma unroll
    for (int fr = 0; fr < 2; fr++)
#pragma unroll
        for (int fn = 0; fn < 4; fn++) {
            float bj = bias[j0 + fn * 16 + ql];
#pragma unroll
            for (int r = 0; r < 4; r++) {
                int m = row0 + w * 32 + fr * 16 + lg * 4 + r;
                out[(size_t)m * CC + j0 + fn * 16 + ql] = acc[fr][fn][r] + bj;
            }
        }
}

extern "C" void kernel_launch(void* const* d_in, const int* in_sizes, int n_in,
                              void* d_out, int out_size, void* d_ws, size_t ws_size,
                              hipStream_t stream) {
    const float* x    = (const float*)d_in[0];
    const float* sinp = (const float*)d_in[1];
    const float* cosp = (const float*)d_in[2];
    const float* wqkv = (const float*)d_in[3];
    const float* bqkv = (const float*)d_in[4];
    const float* wout = (const float*)d_in[5];
    const float* bout = (const float*)d_in[6];
    float* out = (float*)d_out;
    char* ws = (char*)d_ws;

    unsigned short* xb  = (unsigned short*)(ws);            // 4096x768 bf16
    unsigned short* wqb = (unsigned short*)(ws + 6291456);  // Wt_qkv [2304][768]
    unsigned short* wob = (unsigned short*)(ws + 9830400);  // Wt_out [768][768]
    unsigned short* qws = (unsigned short*)(ws + 11010048);
    unsigned short* kws = (unsigned short*)(ws + 17301504);
    unsigned short* vws = (unsigned short*)(ws + 23592960);
    unsigned short* yws = (unsigned short*)(ws + 29884416);
    if (ws_size < 36175872) return;

    k_cvt<<<dim3(512), dim3(256), 0, stream>>>(x, xb, MM * CC / 4);
    k_cvtT<<<dim3(36, 12), dim3(256), 0, stream>>>(wqkv, wqb, CC, N3);
    k_cvtT<<<dim3(12, 12), dim3(256), 0, stream>>>(wout, wob, CC, CC);
    k_qkv<<<dim3(32, 36), dim3(256), 0, stream>>>(xb, wqb, bqkv, sinp, cosp, qws, kws, vws);
    k_attn<<<dim3(768), dim3(128), 0, stream>>>(qws, kws, vws, yws);
    k_out<<<dim3(32, 12), dim3(256), 0, stream>>>(yws, wob, bout, out);
}